// Round 6
// baseline (188.290 us; speedup 1.0000x reference)
//
#include <hip/hip_runtime.h>

#define B_ 8
#define C_ 512
#define N_ 1024
#define GROUPS_ 32
#define CPG_ 16
#define NH_ 8
#define HD_ 64

typedef _Float16 half8 __attribute__((ext_vector_type(8)));
typedef _Float16 half2v __attribute__((ext_vector_type(2)));
typedef float f32x4 __attribute__((ext_vector_type(4)));
typedef float f32x16 __attribute__((ext_vector_type(16)));

// 0.125 (qk softmax scale) * log2(e): folded into Q weights -> exp2-domain softmax
#define QSCALE 0.18033688011112042f
#define THR_LOG2 11.0f

// async global->LDS, 16B per lane; LDS dest is wave-uniform base + lane*16
__device__ __forceinline__ void gload_lds16(const void* g, void* l) {
  __builtin_amdgcn_global_load_lds(
      (const __attribute__((address_space(1))) unsigned int*)g,
      (__attribute__((address_space(3))) unsigned int*)l, 16, 0, 0);
}

// ---------------------------------------------------------------------------
// prep: blocks 0..511 pack weights fp32->fp16 (reordered);
//       blocks 512..767 compute GroupNorm stats.
// ---------------------------------------------------------------------------
__global__ __launch_bounds__(256) void prep(
    const float* __restrict__ qkv_w, const float* __restrict__ proj_w,
    const float* __restrict__ x, _Float16* __restrict__ qkw,
    _Float16* __restrict__ vw, _Float16* __restrict__ pw,
    float2* __restrict__ stats) {
  const int tid = threadIdx.x;
  if (blockIdx.x < 512) {
    const int R = blockIdx.x * 4 + (tid >> 6);
    const int k = (tid & 63) * 8;
    const float* src;
    _Float16* dst;
    float sc = 1.f;
    if (R < 1024) {
      const int head = R >> 7, r = R & 127;
      src = qkv_w + (size_t)(head * 192 + r) * 512;
      if (r < 64) sc = QSCALE;
      dst = qkw + (size_t)R * 512;
    } else if (R < 1536) {
      const int vr = R - 1024;
      const int head = vr >> 6, c = vr & 63;
      src = qkv_w + (size_t)(head * 192 + 128 + c) * 512;
      dst = vw + (size_t)vr * 512;
    } else {
      src = proj_w + (size_t)(R - 1536) * 512;
      dst = pw + (size_t)(R - 1536) * 512;
    }
    const float4 v0 = *reinterpret_cast<const float4*>(src + k);
    const float4 v1 = *reinterpret_cast<const float4*>(src + k + 4);
    _Float16 h[8] = {(_Float16)(v0.x * sc), (_Float16)(v0.y * sc),
                     (_Float16)(v0.z * sc), (_Float16)(v0.w * sc),
                     (_Float16)(v1.x * sc), (_Float16)(v1.y * sc),
                     (_Float16)(v1.z * sc), (_Float16)(v1.w * sc)};
    *reinterpret_cast<float4*>(dst + k) = *reinterpret_cast<float4*>(h);
  } else {
    const int bg = blockIdx.x - 512;
    const int b = bg / GROUPS_, g = bg % GROUPS_;
    const float* xp = x + ((size_t)b * C_ + (size_t)g * CPG_) * N_;
    const int total = CPG_ * N_;
    float s = 0.f, ss = 0.f;
    for (int i = tid * 4; i < total; i += 1024) {
      const float4 v = *reinterpret_cast<const float4*>(xp + i);
      s += v.x + v.y + v.z + v.w;
      ss += v.x * v.x + v.y * v.y + v.z * v.z + v.w * v.w;
    }
#pragma unroll
    for (int off = 32; off > 0; off >>= 1) {
      s += __shfl_down(s, off);
      ss += __shfl_down(ss, off);
    }
    __shared__ float red[8];
    if ((tid & 63) == 0) { red[tid >> 6] = s; red[4 + (tid >> 6)] = ss; }
    __syncthreads();
    if (tid == 0) {
      s = red[0] + red[1] + red[2] + red[3];
      ss = red[4] + red[5] + red[6] + red[7];
      const float inv = 1.0f / (float)total;
      const float mu = s * inv;
      const float var = ss * inv - mu * mu;
      stats[bg] = make_float2(mu, rsqrtf(var + 1e-5f));
    }
  }
}

// ---------------------------------------------------------------------------
// GroupNorm normalize + transpose to xnT[b][n][c] fp16 (1KB coalesced rows).
// ---------------------------------------------------------------------------
__global__ __launch_bounds__(256) void gn_norm(const float* __restrict__ x,
                                               const float* __restrict__ gw,
                                               const float* __restrict__ gb,
                                               const float2* __restrict__ stats,
                                               _Float16* __restrict__ xnT) {
  const int n0 = blockIdx.x * 16;
  const int b = blockIdx.y;
  __shared__ _Float16 T[16][520];
  __shared__ float wsh[512], bsh[512];
  const int tid = threadIdx.x;
  for (int c = tid; c < 512; c += 256) {
    const float2 st = stats[b * 32 + (c >> 4)];
    const float wv = gw[c] * st.y;
    wsh[c] = wv;
    bsh[c] = gb[c] - st.x * wv;
  }
  __syncthreads();
  {
    const int n = tid & 15;
    const int cb = tid >> 4;
    const float* xb = x + (size_t)b * C_ * N_ + n0 + n;
#pragma unroll
    for (int i = 0; i < 32; ++i) {
      const int c = i * 16 + cb;
      T[n][c] = (_Float16)(xb[(size_t)c * N_] * wsh[c] + bsh[c]);
    }
  }
  __syncthreads();
  const int row = tid >> 4;
  const int seg = tid & 15;
  _Float16* dst = &xnT[((size_t)b * N_ + n0 + row) * C_ + seg * 32];
  const _Float16* srcp = &T[row][seg * 32];
  *reinterpret_cast<float4*>(dst) = *reinterpret_cast<const float4*>(srcp);
  *reinterpret_cast<float4*>(dst + 8) = *reinterpret_cast<const float4*>(srcp + 8);
  *reinterpret_cast<float4*>(dst + 16) = *reinterpret_cast<const float4*>(srcp + 16);
  *reinterpret_cast<float4*>(dst + 24) = *reinterpret_cast<const float4*>(srcp + 24);
}

// ---------------------------------------------------------------------------
// Merged QK + V GEMM (one launch, 768 blocks):
//  y<8 : qkT[b][n][ch] = sum_k xnT[b][n][k] * qkw[ch][k]   (ar=n, bc=ch)
//  y>=8: vT[b][vr][n]  = sum_k vw[vr][k]   * xnT[b][n][k]  (ar=vr, bc=n)
// 128x128 tile, BK=64, dbuf LDS via global_load_lds, XOR-swizzled granules.
// ---------------------------------------------------------------------------
__global__ __launch_bounds__(256, 2) void gemm_qkv(
    const _Float16* __restrict__ xnT, const _Float16* __restrict__ qkw,
    const _Float16* __restrict__ vw, _Float16* __restrict__ qkT,
    _Float16* __restrict__ vT) {
  const int b = blockIdx.z;
  const int bc0 = blockIdx.x * 128;
  int ar0;
  const _Float16 *Ab, *Bb;
  _Float16* Dp;
  if (blockIdx.y < 8) {
    ar0 = blockIdx.y * 128;
    Ab = xnT + (size_t)b * N_ * C_;
    Bb = qkw;
    Dp = qkT + (size_t)b * N_ * 1024;
  } else {
    ar0 = (blockIdx.y - 8) * 128;
    Ab = vw;
    Bb = xnT + (size_t)b * N_ * C_;
    Dp = vT + (size_t)b * 512 * 1024;
  }
  const int K = 512;

  __shared__ _Float16 As[2][128][64];
  __shared__ _Float16 Bs[2][128][64];

  const int tid = threadIdx.x;
  const int lane = tid & 63;
  const int wid = tid >> 6;
  const int war = (wid >> 1) * 64;
  const int wbc = (wid & 1) * 64;
  const int lg = lane >> 4;
  const int lr = lane & 15;

  const int srow = lane >> 3;
  const int sgr = (lane & 7) ^ srow;

#define STAGE(buf, koff)                                                     \
  _Pragma("unroll") for (int i = 0; i < 4; ++i) {                            \
    const int rb = (i * 4 + wid) * 8;                                        \
    gload_lds16(&Ab[(size_t)(ar0 + rb + srow) * K + (koff) + sgr * 8],       \
                &As[buf][rb][0]);                                            \
    gload_lds16(&Bb[(size_t)(bc0 + rb + srow) * K + (koff) + sgr * 8],       \
                &Bs[buf][rb][0]);                                            \
  }

  f32x4 acc[4][4] = {};

  STAGE(0, 0)
  __syncthreads();

  int cur = 0;
#pragma unroll 1
  for (int step = 0; step < 8; ++step) {
    if (step + 1 < 8) { STAGE(cur ^ 1, (step + 1) << 6) }
    const half8* Ah = reinterpret_cast<const half8*>(&As[cur][0][0]);
    const half8* Bh = reinterpret_cast<const half8*>(&Bs[cur][0][0]);
#pragma unroll
    for (int kc = 0; kc < 2; ++kc) {
      half8 af[4], bf[4];
#pragma unroll
      for (int i = 0; i < 4; ++i)
        af[i] = Ah[(war + i * 16 + lr) * 8 + ((4 * kc + lg) ^ (lr & 7))];
#pragma unroll
      for (int j = 0; j < 4; ++j)
        bf[j] = Bh[(wbc + j * 16 + lr) * 8 + ((4 * kc + lg) ^ (lr & 7))];
#pragma unroll
      for (int i = 0; i < 4; ++i)
#pragma unroll
        for (int j = 0; j < 4; ++j)
          acc[i][j] = __builtin_amdgcn_mfma_f32_16x16x32_f16(af[i], bf[j],
                                                             acc[i][j], 0, 0, 0);
    }
    __syncthreads();
    cur ^= 1;
  }
#undef STAGE

#pragma unroll
  for (int i = 0; i < 4; ++i)
#pragma unroll
    for (int r = 0; r < 4; ++r) {
      const int row = ar0 + war + i * 16 + lg * 4 + r;
#pragma unroll
      for (int j = 0; j < 4; ++j) {
        const int col = bc0 + wbc + j * 16 + lr;
        Dp[(size_t)row * 1024 + col] = (_Float16)acc[i][j][r];
      }
    }
}

// ---------------------------------------------------------------------------
// Proj GEMM: out[b][c][n] = sum_k pw[c][k]*hT[b][n][k] + proj_b[c] + x[b][c][n]
// 128(M=c) x 64(N=n) tile, BK=64 dbuf, 512 blocks (2/CU).
// ---------------------------------------------------------------------------
__global__ __launch_bounds__(256, 2) void gemm_proj(
    const _Float16* __restrict__ pw, const _Float16* __restrict__ hT,
    float* __restrict__ out, const float* __restrict__ bias,
    const float* __restrict__ resid) {
  const int bc0 = blockIdx.x * 64;   // n
  const int ar0 = blockIdx.y * 128;  // c
  const int b = blockIdx.z;
  const _Float16* Bb = hT + (size_t)b * N_ * C_;
  const int K = 512;

  __shared__ _Float16 As[2][128][64];
  __shared__ _Float16 Bs[2][64][64];

  const int tid = threadIdx.x;
  const int lane = tid & 63;
  const int wid = tid >> 6;
  const int war = (wid >> 1) * 64;
  const int wbc = (wid & 1) * 32;
  const int lg = lane >> 4;
  const int lr = lane & 15;

  const int srow = lane >> 3;
  const int sgr = (lane & 7) ^ srow;

#define STAGEP(buf, koff)                                                    \
  _Pragma("unroll") for (int i = 0; i < 4; ++i) {                            \
    const int rb = (i * 4 + wid) * 8;                                        \
    gload_lds16(&pw[(size_t)(ar0 + rb + srow) * K + (koff) + sgr * 8],       \
                &As[buf][rb][0]);                                            \
  }                                                                          \
  _Pragma("unroll") for (int i = 0; i < 2; ++i) {                            \
    const int rb = (i * 4 + wid) * 8;                                        \
    gload_lds16(&Bb[(size_t)(bc0 + rb + srow) * K + (koff) + sgr * 8],       \
                &Bs[buf][rb][0]);                                            \
  }

  f32x4 acc[4][2] = {};

  STAGEP(0, 0)
  __syncthreads();

  int cur = 0;
#pragma unroll 1
  for (int step = 0; step < 8; ++step) {
    if (step + 1 < 8) { STAGEP(cur ^ 1, (step + 1) << 6) }
    const half8* Ah = reinterpret_cast<const half8*>(&As[cur][0][0]);
    const half8* Bh = reinterpret_cast<const half8*>(&Bs[cur][0][0]);
#pragma unroll
    for (int kc = 0; kc < 2; ++kc) {
      half8 af[4], bf[2];
#pragma unroll
      for (int i = 0; i < 4; ++i)
        af[i] = Ah[(war + i * 16 + lr) * 8 + ((4 * kc + lg) ^ (lr & 7))];
#pragma unroll
      for (int j = 0; j < 2; ++j)
        bf[j] = Bh[(wbc + j * 16 + lr) * 8 + ((4 * kc + lg) ^ (lr & 7))];
#pragma unroll
      for (int i = 0; i < 4; ++i)
#pragma unroll
        for (int j = 0; j < 2; ++j)
          acc[i][j] = __builtin_amdgcn_mfma_f32_16x16x32_f16(af[i], bf[j],
                                                             acc[i][j], 0, 0, 0);
    }
    __syncthreads();
    cur ^= 1;
  }
#undef STAGEP

  float* Dp = out + (size_t)b * C_ * N_;
  const float* Rp = resid + (size_t)b * C_ * N_;
#pragma unroll
  for (int i = 0; i < 4; ++i)
#pragma unroll
    for (int r = 0; r < 4; ++r) {
      const int row = ar0 + war + i * 16 + lg * 4 + r;
      const float bv = bias[row];
#pragma unroll
      for (int j = 0; j < 2; ++j) {
        const int col = bc0 + wbc + j * 16 + lr;
        const size_t off = (size_t)row * N_ + col;
        Dp[off] = acc[i][j][r] + bv + Rp[off];
      }
    }
}

// ---------------------------------------------------------------------------
// Flash attention, 32x32x16 MFMA, swapped QK^T, in-register P.
// NO LDS, NO BARRIERS: K/V per head is L1/L2-resident (256 KB), fragments
// loaded per-lane directly from global in MFMA order. Waves fully independent.
// bid = qt*64 + bh  ->  all 8 q-tiles of a head share one XCD's L2.
// K software-pipelined (t+1 loads issued mid-softmax); V issued before softmax.
// ---------------------------------------------------------------------------
__global__ __launch_bounds__(256, 2) void attn_mfma(
    const _Float16* __restrict__ qkT, const _Float16* __restrict__ vT,
    _Float16* __restrict__ hT) {
  const int bid = blockIdx.x;
  const int qt = bid >> 6;   // 0..7
  const int bh = bid & 63;   // same-XCD for all qt of this bh
  const int b = bh >> 3, head = bh & 7;
  const int qb = qt * 128;
  const int tid = threadIdx.x;
  const int lane = tid & 63;
  const int w = tid >> 6;
  const int l31 = lane & 31;
  const int lg2 = lane >> 5;

  const size_t qkbase = (size_t)b * N_ * 1024;
  const _Float16* kbase =
      qkT + qkbase + head * 128 + 64 + (size_t)l31 * 1024 + lg2 * 8;
  const _Float16* vbase =
      vT + ((size_t)bh * 64 + l31) * 1024 + lg2 * 8;

  // Q fragments in registers (pre-scaled by QSCALE at weight pack)
  half8 bfq[4];
#pragma unroll
  for (int kc = 0; kc < 4; ++kc)
    bfq[kc] = *reinterpret_cast<const half8*>(
        &qkT[qkbase + (size_t)(qb + w * 32 + l31) * 1024 + head * 128 +
             kc * 16 + lg2 * 8]);

  f32x16 oacc[2];
#pragma unroll
  for (int ct = 0; ct < 2; ++ct)
#pragma unroll
    for (int r = 0; r < 16; ++r) oacc[ct][r] = 0.f;
  float m_run = -1e30f, l_run = 0.f;

  // K fragments for tile 0
  half8 kf[2][4];
#pragma unroll
  for (int st = 0; st < 2; ++st)
#pragma unroll
    for (int kc = 0; kc < 4; ++kc)
      kf[st][kc] = *reinterpret_cast<const half8*>(
          kbase + (size_t)(st * 32) * 1024 + kc * 16);

#pragma unroll 1
  for (int t = 0; t < 16; ++t) {
    const int sb = t * 64;

    // S^T = K·Q (one query column per lane)
    f32x16 sacc[2];
#pragma unroll
    for (int st = 0; st < 2; ++st)
#pragma unroll
      for (int r = 0; r < 16; ++r) sacc[st][r] = 0.f;
    __builtin_amdgcn_s_setprio(1);
#pragma unroll
    for (int st = 0; st < 2; ++st)
#pragma unroll
      for (int kc = 0; kc < 4; ++kc)
        sacc[st] = __builtin_amdgcn_mfma_f32_32x32x16_f16(kf[st][kc], bfq[kc],
                                                          sacc[st], 0, 0, 0);
    __builtin_amdgcn_s_setprio(0);

    // issue V fragment loads now; consumed after softmax (latency hidden)
    half8 vf[2][4];
#pragma unroll
    for (int ct = 0; ct < 2; ++ct)
#pragma unroll
      for (int ks = 0; ks < 4; ++ks)
        vf[ct][ks] = *reinterpret_cast<const half8*>(
            vbase + (size_t)(ct * 32) * 1024 + sb + ks * 16);

    // online softmax (exp2 domain), defer-max; 4-chain max reduce
    float mx0 = sacc[0][0], mx1 = sacc[0][1], mx2 = sacc[0][2], mx3 = sacc[0][3];
#pragma unroll
    for (int st = 0; st < 2; ++st)
#pragma unroll
      for (int r = (st ? 0 : 4); r < 16; r += 4) {
        mx0 = fmaxf(mx0, sacc[st][r]);
        mx1 = fmaxf(mx1, sacc[st][r + 1]);
        mx2 = fmaxf(mx2, sacc[st][r + 2]);
        mx3 = fmaxf(mx3, sacc[st][r + 3]);
      }
    float mt = fmaxf(fmaxf(mx0, mx1), fmaxf(mx2, mx3));
    mt = fmaxf(mt, __shfl_xor(mt, 32));
    if (!__all(mt <= m_run + THR_LOG2)) {
      const float mn = fmaxf(m_run, mt);
      const float alpha = exp2f(m_run - mn);
      m_run = mn;
      l_run *= alpha;
#pragma unroll
      for (int r = 0; r < 16; ++r) {
        const int qrow = (r & 3) + 8 * (r >> 2) + 4 * lg2;
        const float ar = __shfl(alpha, qrow);
        oacc[0][r] *= ar;
        oacc[1][r] *= ar;
      }
    }
    const float mr = m_run;
    float ps0 = 0.f, ps1 = 0.f, ps2 = 0.f, ps3 = 0.f;
#pragma unroll
    for (int st = 0; st < 2; ++st)
#pragma unroll
      for (int r = 0; r < 16; r += 4) {
        float p0 = exp2f(sacc[st][r] - mr);
        float p1 = exp2f(sacc[st][r + 1] - mr);
        float p2 = exp2f(sacc[st][r + 2] - mr);
        float p3 = exp2f(sacc[st][r + 3] - mr);
        sacc[st][r] = p0;
        sacc[st][r + 1] = p1;
        sacc[st][r + 2] = p2;
        sacc[st][r + 3] = p3;
        ps0 += p0; ps1 += p1; ps2 += p2; ps3 += p3;
      }
    float ps = (ps0 + ps1) + (ps2 + ps3);
    ps += __shfl_xor(ps, 32);
    l_run += ps;

    // prefetch K fragments for t+1 (consumed next iteration)
    {
      const int sbn = (t < 15) ? (t + 1) * 64 : 960;
#pragma unroll
      for (int st = 0; st < 2; ++st)
#pragma unroll
        for (int kc = 0; kc < 4; ++kc)
          kf[st][kc] = *reinterpret_cast<const half8*>(
              kbase + (size_t)(sbn + st * 32) * 1024 + kc * 16);
    }

    // pack P -> PV A-fragments (cross-half exchange via shfl_xor 32)
    half8 pa[4];
    {
      unsigned int wo[2][8];
#pragma unroll
      for (int st = 0; st < 2; ++st)
#pragma unroll
        for (int m = 0; m < 8; ++m) {
          union { half2v h; unsigned int u; } cv;
          cv.h.x = (_Float16)sacc[st][2 * m];
          cv.h.y = (_Float16)sacc[st][2 * m + 1];
          wo[st][m] = cv.u;
        }
#pragma unroll
      for (int kc = 0; kc < 4; ++kc) {
        const int st = kc >> 1;
        const int base = 4 * (kc & 1);
        const unsigned int a0 = wo[st][base], a1 = wo[st][base + 1];
        const unsigned int a2 = wo[st][base + 2], a3 = wo[st][base + 3];
        const unsigned int x0 = __shfl_xor(a0, 32);
        const unsigned int x1 = __shfl_xor(a1, 32);
        const unsigned int x2 = __shfl_xor(a2, 32);
        const unsigned int x3 = __shfl_xor(a3, 32);
        union { unsigned int u[4]; half8 h; } fr;
        fr.u[0] = lg2 ? x2 : a0;
        fr.u[1] = lg2 ? x3 : a1;
        fr.u[2] = lg2 ? a2 : x0;
        fr.u[3] = lg2 ? a3 : x1;
        pa[kc] = fr.h;
      }
    }

    // O += P·V
    __builtin_amdgcn_s_setprio(1);
#pragma unroll
    for (int ct = 0; ct < 2; ++ct)
#pragma unroll
      for (int ks = 0; ks < 4; ++ks)
        oacc[ct] = __builtin_amdgcn_mfma_f32_32x32x16_f16(pa[ks], vf[ct][ks],
                                                          oacc[ct], 0, 0, 0);
    __builtin_amdgcn_s_setprio(0);
  }

  const size_t hbase = ((size_t)b * N_ + qb) * C_ + head * 64;
  const float linv = 1.f / l_run;
#pragma unroll
  for (int r = 0; r < 16; ++r) {
    const int qrow = (r & 3) + 8 * (r >> 2) + 4 * lg2;
    const float li = __shfl(linv, qrow);
    const size_t rowoff = hbase + (size_t)(w * 32 + qrow) * C_;
#pragma unroll
    for (int ct = 0; ct < 2; ++ct)
      hT[rowoff + ct * 32 + l31] = (_Float16)(oacc[ct][r] * li);
  }
}

// ---------------------------------------------------------------------------
extern "C" void kernel_launch(void* const* d_in, const int* in_sizes, int n_in,
                              void* d_out, int out_size, void* d_ws,
                              size_t ws_size, hipStream_t stream) {
  const float* x = (const float*)d_in[0];
  const float* gn_w = (const float*)d_in[1];
  const float* gn_b = (const float*)d_in[2];
  const float* qkv_w = (const float*)d_in[3];
  const float* proj_w = (const float*)d_in[4];
  const float* proj_b = (const float*)d_in[5];
  float* out = (float*)d_out;

  char* ws = (char*)d_ws;
  const size_t MB = 1024 * 1024;
  _Float16* qkw = (_Float16*)(ws);                 // 1 MiB
  _Float16* vw = (_Float16*)(ws + 1 * MB);         // 0.5 MiB
  _Float16* pw = (_Float16*)(ws + 3 * MB / 2);     // 0.5 MiB
  float2* stats = (float2*)(ws + 2 * MB);          // 2 KiB
  _Float16* xnT = (_Float16*)(ws + 3 * MB);        // 8 MiB  [b][n][512]
  _Float16* qkT = (_Float16*)(ws + 11 * MB);       // 16 MiB [b][n][1024]
  _Float16* vT = (_Float16*)(ws + 27 * MB);        // 8 MiB  [b][vr][n]
  _Float16* hT = (_Float16*)(ws + 35 * MB);        // 8 MiB  [b][n][512]

  prep<<<dim3(768), 256, 0, stream>>>(qkv_w, proj_w, x, qkw, vw, pw, stats);
  gn_norm<<<dim3(64, B_), 256, 0, stream>>>(x, gn_w, gn_b, stats, xnT);
  gemm_qkv<<<dim3(8, 12, B_), 256, 0, stream>>>(xnT, qkw, vw, qkT, vT);
  attn_mfma<<<dim3(512), 256, 0, stream>>>(qkT, vT, hT);
  gemm_proj<<<dim3(16, 4, B_), 256, 0, stream>>>(pw, hT, out, proj_b, x);
}

// Round 9
// 173.452 us; speedup vs baseline: 1.0855x; 1.0855x over previous
//
#include <hip/hip_runtime.h>

#define B_ 8
#define C_ 512
#define N_ 1024
#define GROUPS_ 32
#define CPG_ 16
#define NH_ 8
#define HD_ 64

typedef _Float16 half8 __attribute__((ext_vector_type(8)));
typedef _Float16 half2v __attribute__((ext_vector_type(2)));
typedef float f32x4 __attribute__((ext_vector_type(4)));
typedef float f32x16 __attribute__((ext_vector_type(16)));

// 0.125 (qk softmax scale) * log2(e): folded into Q weights -> exp2-domain softmax
#define QSCALE 0.18033688011112042f
#define THR_LOG2 11.0f

// async global->LDS, 16B per lane; LDS dest is wave-uniform base + lane*16
__device__ __forceinline__ void gload_lds16(const void* g, void* l) {
  __builtin_amdgcn_global_load_lds(
      (const __attribute__((address_space(1))) unsigned int*)g,
      (__attribute__((address_space(3))) unsigned int*)l, 16, 0, 0);
}

// ---------------------------------------------------------------------------
// prep: blocks 0..511 pack weights fp32->fp16 (reordered);
//       blocks 512..767 compute GroupNorm stats.
// ---------------------------------------------------------------------------
__global__ __launch_bounds__(256) void prep(
    const float* __restrict__ qkv_w, const float* __restrict__ proj_w,
    const float* __restrict__ x, _Float16* __restrict__ qkw,
    _Float16* __restrict__ vw, _Float16* __restrict__ pw,
    float2* __restrict__ stats) {
  const int tid = threadIdx.x;
  if (blockIdx.x < 512) {
    const int R = blockIdx.x * 4 + (tid >> 6);
    const int k = (tid & 63) * 8;
    const float* src;
    _Float16* dst;
    float sc = 1.f;
    if (R < 1024) {
      const int head = R >> 7, r = R & 127;
      src = qkv_w + (size_t)(head * 192 + r) * 512;
      if (r < 64) sc = QSCALE;
      dst = qkw + (size_t)R * 512;
    } else if (R < 1536) {
      const int vr = R - 1024;
      const int head = vr >> 6, c = vr & 63;
      src = qkv_w + (size_t)(head * 192 + 128 + c) * 512;
      dst = vw + (size_t)vr * 512;
    } else {
      src = proj_w + (size_t)(R - 1536) * 512;
      dst = pw + (size_t)(R - 1536) * 512;
    }
    const float4 v0 = *reinterpret_cast<const float4*>(src + k);
    const float4 v1 = *reinterpret_cast<const float4*>(src + k + 4);
    _Float16 h[8] = {(_Float16)(v0.x * sc), (_Float16)(v0.y * sc),
                     (_Float16)(v0.z * sc), (_Float16)(v0.w * sc),
                     (_Float16)(v1.x * sc), (_Float16)(v1.y * sc),
                     (_Float16)(v1.z * sc), (_Float16)(v1.w * sc)};
    *reinterpret_cast<float4*>(dst + k) = *reinterpret_cast<float4*>(h);
  } else {
    const int bg = blockIdx.x - 512;
    const int b = bg / GROUPS_, g = bg % GROUPS_;
    const float* xp = x + ((size_t)b * C_ + (size_t)g * CPG_) * N_;
    const int total = CPG_ * N_;
    float s = 0.f, ss = 0.f;
    for (int i = tid * 4; i < total; i += 1024) {
      const float4 v = *reinterpret_cast<const float4*>(xp + i);
      s += v.x + v.y + v.z + v.w;
      ss += v.x * v.x + v.y * v.y + v.z * v.z + v.w * v.w;
    }
#pragma unroll
    for (int off = 32; off > 0; off >>= 1) {
      s += __shfl_down(s, off);
      ss += __shfl_down(ss, off);
    }
    __shared__ float red[8];
    if ((tid & 63) == 0) { red[tid >> 6] = s; red[4 + (tid >> 6)] = ss; }
    __syncthreads();
    if (tid == 0) {
      s = red[0] + red[1] + red[2] + red[3];
      ss = red[4] + red[5] + red[6] + red[7];
      const float inv = 1.0f / (float)total;
      const float mu = s * inv;
      const float var = ss * inv - mu * mu;
      stats[bg] = make_float2(mu, rsqrtf(var + 1e-5f));
    }
  }
}

// ---------------------------------------------------------------------------
// GroupNorm normalize + transpose to xnT[b][n][c] fp16 (1KB coalesced rows).
// ---------------------------------------------------------------------------
__global__ __launch_bounds__(256) void gn_norm(const float* __restrict__ x,
                                               const float* __restrict__ gw,
                                               const float* __restrict__ gb,
                                               const float2* __restrict__ stats,
                                               _Float16* __restrict__ xnT) {
  const int n0 = blockIdx.x * 16;
  const int b = blockIdx.y;
  __shared__ _Float16 T[16][520];
  __shared__ float wsh[512], bsh[512];
  const int tid = threadIdx.x;
  for (int c = tid; c < 512; c += 256) {
    const float2 st = stats[b * 32 + (c >> 4)];
    const float wv = gw[c] * st.y;
    wsh[c] = wv;
    bsh[c] = gb[c] - st.x * wv;
  }
  __syncthreads();
  {
    const int n = tid & 15;
    const int cb = tid >> 4;
    const float* xb = x + (size_t)b * C_ * N_ + n0 + n;
#pragma unroll
    for (int i = 0; i < 32; ++i) {
      const int c = i * 16 + cb;
      T[n][c] = (_Float16)(xb[(size_t)c * N_] * wsh[c] + bsh[c]);
    }
  }
  __syncthreads();
  const int row = tid >> 4;
  const int seg = tid & 15;
  _Float16* dst = &xnT[((size_t)b * N_ + n0 + row) * C_ + seg * 32];
  const _Float16* srcp = &T[row][seg * 32];
  *reinterpret_cast<float4*>(dst) = *reinterpret_cast<const float4*>(srcp);
  *reinterpret_cast<float4*>(dst + 8) = *reinterpret_cast<const float4*>(srcp + 8);
  *reinterpret_cast<float4*>(dst + 16) = *reinterpret_cast<const float4*>(srcp + 16);
  *reinterpret_cast<float4*>(dst + 24) = *reinterpret_cast<const float4*>(srcp + 24);
}

// ---------------------------------------------------------------------------
// Merged QK + V GEMM (one launch, 768 blocks):
//  y<8 : qkT[b][n][ch] = sum_k xnT[b][n][k] * qkw[ch][k]   (ar=n, bc=ch)
//  y>=8: vT[b][vr][n]  = sum_k vw[vr][k]   * xnT[b][n][k]  (ar=vr, bc=n)
// 128x128 tile, BK=64, dbuf LDS via global_load_lds, XOR-swizzled granules.
// ---------------------------------------------------------------------------
__global__ __launch_bounds__(256, 2) void gemm_qkv(
    const _Float16* __restrict__ xnT, const _Float16* __restrict__ qkw,
    const _Float16* __restrict__ vw, _Float16* __restrict__ qkT,
    _Float16* __restrict__ vT) {
  const int b = blockIdx.z;
  const int bc0 = blockIdx.x * 128;
  int ar0;
  const _Float16 *Ab, *Bb;
  _Float16* Dp;
  if (blockIdx.y < 8) {
    ar0 = blockIdx.y * 128;
    Ab = xnT + (size_t)b * N_ * C_;
    Bb = qkw;
    Dp = qkT + (size_t)b * N_ * 1024;
  } else {
    ar0 = (blockIdx.y - 8) * 128;
    Ab = vw;
    Bb = xnT + (size_t)b * N_ * C_;
    Dp = vT + (size_t)b * 512 * 1024;
  }
  const int K = 512;

  __shared__ _Float16 As[2][128][64];
  __shared__ _Float16 Bs[2][128][64];

  const int tid = threadIdx.x;
  const int lane = tid & 63;
  const int wid = tid >> 6;
  const int war = (wid >> 1) * 64;
  const int wbc = (wid & 1) * 64;
  const int lg = lane >> 4;
  const int lr = lane & 15;

  const int srow = lane >> 3;
  const int sgr = (lane & 7) ^ srow;

#define STAGE(buf, koff)                                                     \
  _Pragma("unroll") for (int i = 0; i < 4; ++i) {                            \
    const int rb = (i * 4 + wid) * 8;                                        \
    gload_lds16(&Ab[(size_t)(ar0 + rb + srow) * K + (koff) + sgr * 8],       \
                &As[buf][rb][0]);                                            \
    gload_lds16(&Bb[(size_t)(bc0 + rb + srow) * K + (koff) + sgr * 8],       \
                &Bs[buf][rb][0]);                                            \
  }

  f32x4 acc[4][4] = {};

  STAGE(0, 0)
  __syncthreads();

  int cur = 0;
#pragma unroll 1
  for (int step = 0; step < 8; ++step) {
    if (step + 1 < 8) { STAGE(cur ^ 1, (step + 1) << 6) }
    const half8* Ah = reinterpret_cast<const half8*>(&As[cur][0][0]);
    const half8* Bh = reinterpret_cast<const half8*>(&Bs[cur][0][0]);
#pragma unroll
    for (int kc = 0; kc < 2; ++kc) {
      half8 af[4], bf[4];
#pragma unroll
      for (int i = 0; i < 4; ++i)
        af[i] = Ah[(war + i * 16 + lr) * 8 + ((4 * kc + lg) ^ (lr & 7))];
#pragma unroll
      for (int j = 0; j < 4; ++j)
        bf[j] = Bh[(wbc + j * 16 + lr) * 8 + ((4 * kc + lg) ^ (lr & 7))];
#pragma unroll
      for (int i = 0; i < 4; ++i)
#pragma unroll
        for (int j = 0; j < 4; ++j)
          acc[i][j] = __builtin_amdgcn_mfma_f32_16x16x32_f16(af[i], bf[j],
                                                             acc[i][j], 0, 0, 0);
    }
    __syncthreads();
    cur ^= 1;
  }
#undef STAGE

#pragma unroll
  for (int i = 0; i < 4; ++i)
#pragma unroll
    for (int r = 0; r < 4; ++r) {
      const int row = ar0 + war + i * 16 + lg * 4 + r;
#pragma unroll
      for (int j = 0; j < 4; ++j) {
        const int col = bc0 + wbc + j * 16 + lr;
        Dp[(size_t)row * 1024 + col] = (_Float16)acc[i][j][r];
      }
    }
}

// ---------------------------------------------------------------------------
// Proj GEMM: out[b][c][n] = sum_k pw[c][k]*hT[b][n][k] + proj_b[c] + x[b][c][n]
// 128(M=c) x 64(N=n) tile, BK=64 dbuf, 512 blocks (2/CU).
// ---------------------------------------------------------------------------
__global__ __launch_bounds__(256, 2) void gemm_proj(
    const _Float16* __restrict__ pw, const _Float16* __restrict__ hT,
    float* __restrict__ out, const float* __restrict__ bias,
    const float* __restrict__ resid) {
  const int bc0 = blockIdx.x * 64;   // n
  const int ar0 = blockIdx.y * 128;  // c
  const int b = blockIdx.z;
  const _Float16* Bb = hT + (size_t)b * N_ * C_;
  const int K = 512;

  __shared__ _Float16 As[2][128][64];
  __shared__ _Float16 Bs[2][64][64];

  const int tid = threadIdx.x;
  const int lane = tid & 63;
  const int wid = tid >> 6;
  const int war = (wid >> 1) * 64;
  const int wbc = (wid & 1) * 32;
  const int lg = lane >> 4;
  const int lr = lane & 15;

  const int srow = lane >> 3;
  const int sgr = (lane & 7) ^ srow;

#define STAGEP(buf, koff)                                                    \
  _Pragma("unroll") for (int i = 0; i < 4; ++i) {                            \
    const int rb = (i * 4 + wid) * 8;                                        \
    gload_lds16(&pw[(size_t)(ar0 + rb + srow) * K + (koff) + sgr * 8],       \
                &As[buf][rb][0]);                                            \
  }                                                                          \
  _Pragma("unroll") for (int i = 0; i < 2; ++i) {                            \
    const int rb = (i * 4 + wid) * 8;                                        \
    gload_lds16(&Bb[(size_t)(bc0 + rb + srow) * K + (koff) + sgr * 8],       \
                &Bs[buf][rb][0]);                                            \
  }

  f32x4 acc[4][2] = {};

  STAGEP(0, 0)
  __syncthreads();

  int cur = 0;
#pragma unroll 1
  for (int step = 0; step < 8; ++step) {
    if (step + 1 < 8) { STAGEP(cur ^ 1, (step + 1) << 6) }
    const half8* Ah = reinterpret_cast<const half8*>(&As[cur][0][0]);
    const half8* Bh = reinterpret_cast<const half8*>(&Bs[cur][0][0]);
#pragma unroll
    for (int kc = 0; kc < 2; ++kc) {
      half8 af[4], bf[2];
#pragma unroll
      for (int i = 0; i < 4; ++i)
        af[i] = Ah[(war + i * 16 + lr) * 8 + ((4 * kc + lg) ^ (lr & 7))];
#pragma unroll
      for (int j = 0; j < 2; ++j)
        bf[j] = Bh[(wbc + j * 16 + lr) * 8 + ((4 * kc + lg) ^ (lr & 7))];
#pragma unroll
      for (int i = 0; i < 4; ++i)
#pragma unroll
        for (int j = 0; j < 2; ++j)
          acc[i][j] = __builtin_amdgcn_mfma_f32_16x16x32_f16(af[i], bf[j],
                                                             acc[i][j], 0, 0, 0);
    }
    __syncthreads();
    cur ^= 1;
  }
#undef STAGEP

  float* Dp = out + (size_t)b * C_ * N_;
  const float* Rp = resid + (size_t)b * C_ * N_;
#pragma unroll
  for (int i = 0; i < 4; ++i)
#pragma unroll
    for (int r = 0; r < 4; ++r) {
      const int row = ar0 + war + i * 16 + lg * 4 + r;
      const float bv = bias[row];
#pragma unroll
      for (int j = 0; j < 2; ++j) {
        const int col = bc0 + wbc + j * 16 + lr;
        const size_t off = (size_t)row * N_ + col;
        Dp[off] = acc[i][j][r] + bv + Rp[off];
      }
    }
}

// ---------------------------------------------------------------------------
// Flash attention, 32x32x16 MFMA, swapped QK^T, in-register P.
// QBLK=64, 2 waves/block, 1024 blocks -> 4 independent blocks/CU (8 waves/CU,
// 4 desynchronized phase streams). K/V dbuf in LDS via global_load_lds with
// XOR-swizzled granules; one __syncthreads per tile (its vmcnt(0) drain
// doubles as the staging-complete guarantee). Pack uses minimal cross-half
// exchange: 8 shfl_xor + 8 selects per tile (send-what-partner-needs).
// ---------------------------------------------------------------------------
__global__ __launch_bounds__(128, 2) void attn_mfma(
    const _Float16* __restrict__ qkT, const _Float16* __restrict__ vT,
    _Float16* __restrict__ hT) {
  const int bid = blockIdx.x;
  const int qt = bid >> 6;   // 0..15
  const int bh = bid & 63;   // same-XCD for all qt of this bh (64%8==0)
  const int b = bh >> 3, head = bh & 7;
  const int qb = qt * 64;
  const int tid = threadIdx.x;
  const int lane = tid & 63;
  const int w = tid >> 6;    // 0..1
  const int l31 = lane & 31;
  const int lg2 = lane >> 5;

  __shared__ _Float16 Ks[2][64][64];  // [s][c], swizzled granules
  __shared__ _Float16 Vs[2][64][64];  // [c][s], swizzled granules

  const size_t qkbase = (size_t)b * N_ * 1024;

  // Q fragments in registers (pre-scaled by QSCALE at weight pack)
  half8 bfq[4];
#pragma unroll
  for (int kc = 0; kc < 4; ++kc)
    bfq[kc] = *reinterpret_cast<const half8*>(
        &qkT[qkbase + (size_t)(qb + w * 32 + l31) * 1024 + head * 128 +
             kc * 16 + lg2 * 8]);

  // staging: wave w covers rows w*32 + i*8 + srow, i=0..3 (8 gloads/wave/tile)
  const int srow = lane >> 3;                    // 0..7
  const int sgrh = ((lane & 7) ^ srow) * 8;      // swizzled granule (halves)
  const _Float16* kp = qkT + qkbase + head * 128 + 64 + sgrh;  // +(sb+row)*1024
  const _Float16* vp = vT + (size_t)bh * 64 * 1024 + sgrh;     // +row*1024+sb

#define STAGEA(buf, sb)                                                       \
  _Pragma("unroll") for (int i = 0; i < 4; ++i) {                             \
    const int rb = w * 32 + i * 8;                                            \
    gload_lds16(kp + (size_t)((sb) + rb + srow) * 1024, &Ks[buf][rb][0]);     \
    gload_lds16(vp + (size_t)(rb + srow) * 1024 + (sb), &Vs[buf][rb][0]);     \
  }

  f32x16 oacc[2];
#pragma unroll
  for (int ct = 0; ct < 2; ++ct)
#pragma unroll
    for (int r = 0; r < 16; ++r) oacc[ct][r] = 0.f;
  float m_run = -1e30f, l_run = 0.f;

  STAGEA(0, 0)
  __syncthreads();

  int cur = 0;
#pragma unroll 1
  for (int t = 0; t < 16; ++t) {
    if (t < 15) { STAGEA(cur ^ 1, (t + 1) * 64) }

    // S^T = K·Q (one query column per lane)
    f32x16 sacc[2];
#pragma unroll
    for (int st = 0; st < 2; ++st)
#pragma unroll
      for (int r = 0; r < 16; ++r) sacc[st][r] = 0.f;
    __builtin_amdgcn_s_setprio(1);
#pragma unroll
    for (int st = 0; st < 2; ++st)
#pragma unroll
      for (int kc = 0; kc < 4; ++kc) {
        const half8 af = *reinterpret_cast<const half8*>(
            &Ks[cur][st * 32 + l31][((kc * 2 + lg2) ^ (l31 & 7)) * 8]);
        sacc[st] = __builtin_amdgcn_mfma_f32_32x32x16_f16(af, bfq[kc],
                                                          sacc[st], 0, 0, 0);
      }
    __builtin_amdgcn_s_setprio(0);

    // online softmax (exp2 domain), defer-max; 4-chain max reduce
    float mx0 = sacc[0][0], mx1 = sacc[0][1], mx2 = sacc[0][2], mx3 = sacc[0][3];
#pragma unroll
    for (int st = 0; st < 2; ++st)
#pragma unroll
      for (int r = (st ? 0 : 4); r < 16; r += 4) {
        mx0 = fmaxf(mx0, sacc[st][r]);
        mx1 = fmaxf(mx1, sacc[st][r + 1]);
        mx2 = fmaxf(mx2, sacc[st][r + 2]);
        mx3 = fmaxf(mx3, sacc[st][r + 3]);
      }
    float mt = fmaxf(fmaxf(mx0, mx1), fmaxf(mx2, mx3));
    mt = fmaxf(mt, __shfl_xor(mt, 32));
    if (!__all(mt <= m_run + THR_LOG2)) {
      const float mn = fmaxf(m_run, mt);
      const float alpha = exp2f(m_run - mn);
      m_run = mn;
      l_run *= alpha;
#pragma unroll
      for (int r = 0; r < 16; ++r) {
        const int qrow = (r & 3) + 8 * (r >> 2) + 4 * lg2;
        const float ar = __shfl(alpha, qrow);
        oacc[0][r] *= ar;
        oacc[1][r] *= ar;
      }
    }
    const float mr = m_run;
    float ps0 = 0.f, ps1 = 0.f, ps2 = 0.f, ps3 = 0.f;
#pragma unroll
    for (int st = 0; st < 2; ++st)
#pragma unroll
      for (int r = 0; r < 16; r += 4) {
        float p0 = exp2f(sacc[st][r] - mr);
        float p1 = exp2f(sacc[st][r + 1] - mr);
        float p2 = exp2f(sacc[st][r + 2] - mr);
        float p3 = exp2f(sacc[st][r + 3] - mr);
        sacc[st][r] = p0;
        sacc[st][r + 1] = p1;
        sacc[st][r + 2] = p2;
        sacc[st][r + 3] = p3;
        ps0 += p0; ps1 += p1; ps2 += p2; ps3 += p3;
      }
    float ps = (ps0 + ps1) + (ps2 + ps3);
    ps += __shfl_xor(ps, 32);
    l_run += ps;

    // pack P -> PV A-fragments; minimal cross-half exchange:
    // lg2=0 lane needs partner's {w0,w1} of each 4-word group; lg2=1 needs
    // partner's {w2,w3}. Send the words the partner needs (2 shfl/kc).
    half8 pa[4];
    {
      unsigned int wo[2][8];
#pragma unroll
      for (int st = 0; st < 2; ++st)
#pragma unroll
        for (int m = 0; m < 8; ++m) {
          union { half2v h; unsigned int u; } cv;
          cv.h.x = (_Float16)sacc[st][2 * m];
          cv.h.y = (_Float16)sacc[st][2 * m + 1];
          wo[st][m] = cv.u;
        }
#pragma unroll
      for (int kc = 0; kc < 4; ++kc) {
        const int st = kc >> 1;
        const int base = 4 * (kc & 1);
        const unsigned int a0 = wo[st][base], a1 = wo[st][base + 1];
        const unsigned int a2 = wo[st][base + 2], a3 = wo[st][base + 3];
        const unsigned int s0 = __shfl_xor(lg2 ? a0 : a2, 32);
        const unsigned int s1 = __shfl_xor(lg2 ? a1 : a3, 32);
        union { unsigned int u[4]; half8 h; } fr;
        fr.u[0] = lg2 ? s0 : a0;
        fr.u[1] = lg2 ? s1 : a1;
        fr.u[2] = lg2 ? a2 : s0;
        fr.u[3] = lg2 ? a3 : s1;
        pa[kc] = fr.h;
      }
    }

    // O += P·V
    __builtin_amdgcn_s_setprio(1);
#pragma unroll
    for (int ct = 0; ct < 2; ++ct)
#pragma unroll
      for (int ks = 0; ks < 4; ++ks) {
        const half8 vf = *reinterpret_cast<const half8*>(
            &Vs[cur][ct * 32 + l31][((ks * 2 + lg2) ^ (l31 & 7)) * 8]);
        oacc[ct] = __builtin_amdgcn_mfma_f32_32x32x16_f16(pa[ks], vf,
                                                          oacc[ct], 0, 0, 0);
      }
    __builtin_amdgcn_s_setprio(0);

    __syncthreads();  // drains vmcnt (next buf staged) + all LDS reads done
    cur ^= 1;
  }
#undef STAGEA

  const size_t hbase = ((size_t)b * N_ + qb) * C_ + head * 64;
  const float linv = 1.f / l_run;
#pragma unroll
  for (int r = 0; r < 16; ++r) {
    const int qrow = (r & 3) + 8 * (r >> 2) + 4 * lg2;
    const float li = __shfl(linv, qrow);
    const size_t rowoff = hbase + (size_t)(w * 32 + qrow) * C_;
#pragma unroll
    for (int ct = 0; ct < 2; ++ct)
      hT[rowoff + ct * 32 + l31] = (_Float16)(oacc[ct][r] * li);
  }
}

// ---------------------------------------------------------------------------
extern "C" void kernel_launch(void* const* d_in, const int* in_sizes, int n_in,
                              void* d_out, int out_size, void* d_ws,
                              size_t ws_size, hipStream_t stream) {
  const float* x = (const float*)d_in[0];
  const float* gn_w = (const float*)d_in[1];
  const float* gn_b = (const float*)d_in[2];
  const float* qkv_w = (const float*)d_in[3];
  const float* proj_w = (const float*)d_in[4];
  const float* proj_b = (const float*)d_in[5];
  float* out = (float*)d_out;

  char* ws = (char*)d_ws;
  const size_t MB = 1024 * 1024;
  _Float16* qkw = (_Float16*)(ws);                 // 1 MiB
  _Float16* vw = (_Float16*)(ws + 1 * MB);         // 0.5 MiB
  _Float16* pw = (_Float16*)(ws + 3 * MB / 2);     // 0.5 MiB
  float2* stats = (float2*)(ws + 2 * MB);          // 2 KiB
  _Float16* xnT = (_Float16*)(ws + 3 * MB);        // 8 MiB  [b][n][512]
  _Float16* qkT = (_Float16*)(ws + 11 * MB);       // 16 MiB [b][n][1024]
  _Float16* vT = (_Float16*)(ws + 27 * MB);        // 8 MiB  [b][vr][n]
  _Float16* hT = (_Float16*)(ws + 35 * MB);        // 8 MiB  [b][n][512]

  prep<<<dim3(768), 256, 0, stream>>>(qkv_w, proj_w, x, qkw, vw, pw, stats);
  gn_norm<<<dim3(64, B_), 256, 0, stream>>>(x, gn_w, gn_b, stats, xnT);
  gemm_qkv<<<dim3(8, 12, B_), 256, 0, stream>>>(xnT, qkw, vw, qkT, vT);
  attn_mfma<<<dim3(1024), 128, 0, stream>>>(qkT, vT, hT);
  gemm_proj<<<dim3(16, 4, B_), 256, 0, stream>>>(pw, hT, out, proj_b, x);
}